// Round 1
// baseline (1366.170 us; speedup 1.0000x reference)
//
#include <hip/hip_runtime.h>
#include <hip/hip_bf16.h>

#define NN 50000
#define EE 800000
#define ETOT 850000
#define NG 500

__device__ __forceinline__ unsigned f2ord(float f) {
    unsigned u = __float_as_uint(f);
    return (u & 0x80000000u) ? ~u : (u | 0x80000000u);
}
__device__ __forceinline__ float ord2f(unsigned o) {
    return (o & 0x80000000u) ? __uint_as_float(o & 0x7fffffffu) : __uint_as_float(~o);
}

// Detect whether index arrays are int64 (stride 2 in 32-bit words) or int32.
// Node ids < 50000 << 2^31, so for int64 every odd word is 0.
__global__ void k_detect(const int* __restrict__ ei, int* __restrict__ flag) {
    int s = 2;
    for (int i = 0; i < 64; ++i) {
        if (ei[2 * i + 1] != 0) { s = 1; break; }
    }
    *flag = s;
}

// C[M,256] = A[M,K] @ B[K,256], fp32 tiled. BM=64,BN=64,BK=16, 256 thr, 4x4/thr.
template <int K>
__global__ __launch_bounds__(256) void k_gemm(const float* __restrict__ A,
                                              const float* __restrict__ B,
                                              float* __restrict__ C, int M) {
    __shared__ float As[16][65];  // [k][m], +1 pad breaks store conflicts
    __shared__ float Bs[16][64];  // [k][n]
    const int m0 = blockIdx.x * 64, n0 = blockIdx.y * 64;
    const int tid = threadIdx.x;
    const int tx = tid & 15, ty = tid >> 4;
    float acc[4][4] = {};
    for (int k0 = 0; k0 < K; k0 += 16) {
        {   // A tile: 64 rows x 16 k
            int c = tid & 15, r0 = tid >> 4;
#pragma unroll
            for (int rr = 0; rr < 4; ++rr) {
                int r = r0 + rr * 16;
                int gm = m0 + r;
                As[c][r] = (gm < M) ? A[gm * K + k0 + c] : 0.f;
            }
        }
        {   // B tile: 16 k x 64 n
            int j = tid & 63, cb = tid >> 6;
#pragma unroll
            for (int cc = 0; cc < 4; ++cc) {
                int k = cb + cc * 4;
                Bs[k][j] = B[(k0 + k) * 256 + n0 + j];
            }
        }
        __syncthreads();
#pragma unroll
        for (int k = 0; k < 16; ++k) {
            float a[4], b[4];
#pragma unroll
            for (int i = 0; i < 4; ++i) a[i] = As[k][ty * 4 + i];
#pragma unroll
            for (int j = 0; j < 4; ++j) b[j] = Bs[k][tx * 4 + j];
#pragma unroll
            for (int i = 0; i < 4; ++i)
#pragma unroll
                for (int j = 0; j < 4; ++j) acc[i][j] += a[i] * b[j];
        }
        __syncthreads();
    }
#pragma unroll
    for (int i = 0; i < 4; ++i) {
        int gm = m0 + ty * 4 + i;
        if (gm < M) {
#pragma unroll
            for (int j = 0; j < 4; ++j)
                C[gm * 256 + n0 + tx * 4 + j] = acc[i][j];
        }
    }
}

// alpha_s[n,h] = dot(h[n,h,:], a_src[h,:]); one block per node, wave = head.
__global__ __launch_bounds__(256) void k_alpha(const float* __restrict__ h,
                                               const float* __restrict__ asrc,
                                               const float* __restrict__ adst,
                                               float* __restrict__ os,
                                               float* __restrict__ od) {
    int n = blockIdx.x;
    int tid = threadIdx.x;  // tid = head*64 + d
    float v = h[n * 256 + tid];
    float s = v * asrc[tid];
    float d = v * adst[tid];
#pragma unroll
    for (int o = 32; o > 0; o >>= 1) {
        s += __shfl_down(s, o);
        d += __shfl_down(d, o);
    }
    if ((tid & 63) == 0) {
        os[n * 4 + (tid >> 6)] = s;
        od[n * 4 + (tid >> 6)] = d;
    }
}

__global__ __launch_bounds__(256) void k_init_layer(unsigned* __restrict__ emax,
                                                    float* __restrict__ den,
                                                    float* __restrict__ xa) {
    int i = blockIdx.x * blockDim.x + threadIdx.x;
    if (i < NN * 4) { emax[i] = 0x007FFFFFu; den[i] = 0.f; }  // ord(-inf)
    if (i < NN * 64) xa[i] = 0.f;
}

__global__ __launch_bounds__(256) void k_zero_pool(float* __restrict__ pool,
                                                   float* __restrict__ cnt) {
    int i = blockIdx.x * blockDim.x + threadIdx.x;
    if (i < NG * 64) pool[i] = 0.f;
    if (i < NG) cnt[i] = 0.f;
}

__device__ __forceinline__ void edge_ids(const int* __restrict__ ei, int st, int e,
                                         int& src, int& dst) {
    if (e < EE) {
        src = ei[(size_t)st * e];
        dst = ei[(size_t)st * (EE + e)];
    } else {
        src = dst = e - EE;  // self-loop
    }
}

__global__ __launch_bounds__(256) void k_edge_max(const int* __restrict__ ei,
                                                  const int* __restrict__ flag,
                                                  const float* __restrict__ as_,
                                                  const float* __restrict__ ad_,
                                                  unsigned* __restrict__ emax) {
    int e = blockIdx.x * blockDim.x + threadIdx.x;
    if (e >= ETOT) return;
    int st = *flag, src, dst;
    edge_ids(ei, st, e, src, dst);
    float4 s4 = *(const float4*)(as_ + src * 4);
    float4 d4 = *(const float4*)(ad_ + dst * 4);
    float v[4] = {s4.x + d4.x, s4.y + d4.y, s4.z + d4.z, s4.w + d4.w};
#pragma unroll
    for (int hh = 0; hh < 4; ++hh) {
        float x = v[hh];
        x = x > 0.f ? x : 0.2f * x;
        atomicMax(&emax[dst * 4 + hh], f2ord(x));
    }
}

__global__ __launch_bounds__(256) void k_edge_sum(const int* __restrict__ ei,
                                                  const int* __restrict__ flag,
                                                  const float* __restrict__ as_,
                                                  const float* __restrict__ ad_,
                                                  const unsigned* __restrict__ emax,
                                                  float* __restrict__ den) {
    int e = blockIdx.x * blockDim.x + threadIdx.x;
    if (e >= ETOT) return;
    int st = *flag, src, dst;
    edge_ids(ei, st, e, src, dst);
    float4 s4 = *(const float4*)(as_ + src * 4);
    float4 d4 = *(const float4*)(ad_ + dst * 4);
    float v[4] = {s4.x + d4.x, s4.y + d4.y, s4.z + d4.z, s4.w + d4.w};
#pragma unroll
    for (int hh = 0; hh < 4; ++hh) {
        float x = v[hh];
        x = x > 0.f ? x : 0.2f * x;
        float m = ord2f(emax[dst * 4 + hh]);
        atomicAdd(&den[dst * 4 + hh], __expf(x - m));
    }
}

// One wave per edge; lane = dim. Head-mean (0.25) folded into alpha so each
// (edge,dim) does a single atomicAdd into xa[N,64].
__global__ __launch_bounds__(256) void k_edge_aggr(const int* __restrict__ ei,
                                                   const int* __restrict__ flag,
                                                   const float* __restrict__ as_,
                                                   const float* __restrict__ ad_,
                                                   const unsigned* __restrict__ emax,
                                                   const float* __restrict__ den,
                                                   const float* __restrict__ h,
                                                   float* __restrict__ xa) {
    int wave = (blockIdx.x * blockDim.x + threadIdx.x) >> 6;
    int lane = threadIdx.x & 63;
    if (wave >= ETOT) return;
    int st = *flag, src, dst;
    edge_ids(ei, st, wave, src, dst);
    float alpha[4];
#pragma unroll
    for (int hh = 0; hh < 4; ++hh) {
        float x = as_[src * 4 + hh] + ad_[dst * 4 + hh];
        x = x > 0.f ? x : 0.2f * x;
        float m = ord2f(emax[dst * 4 + hh]);
        alpha[hh] = 0.25f * __expf(x - m) / den[dst * 4 + hh];
    }
    float sum = 0.f;
#pragma unroll
    for (int hh = 0; hh < 4; ++hh)
        sum += alpha[hh] * h[src * 256 + hh * 64 + lane];
    atomicAdd(&xa[dst * 64 + lane], sum);
}

__global__ __launch_bounds__(256) void k_finalize(float* __restrict__ xa,
                                                  const float* __restrict__ b) {
    int i = blockIdx.x * blockDim.x + threadIdx.x;
    if (i < NN * 64) {
        float v = xa[i] + b[i & 63];
        xa[i] = v > 0.f ? v : 0.f;
    }
}

__global__ __launch_bounds__(256) void k_pool(const float* __restrict__ x3,
                                              const int* __restrict__ batch,
                                              const int* __restrict__ flag,
                                              float* __restrict__ pool,
                                              float* __restrict__ cnt) {
    int wave = (blockIdx.x * blockDim.x + threadIdx.x) >> 6;
    int lane = threadIdx.x & 63;
    if (wave >= NN) return;
    int st = *flag;
    int g = batch[(size_t)st * wave];
    atomicAdd(&pool[g * 64 + lane], x3[wave * 64 + lane]);
    if (lane == 0) atomicAdd(&cnt[g], 1.0f);
}

__global__ __launch_bounds__(64) void k_fc(const float* __restrict__ pool,
                                           const float* __restrict__ cnt,
                                           const float* __restrict__ fcW,
                                           const float* __restrict__ fcb,
                                           float* __restrict__ out) {
    int g = blockIdx.x;
    int d = threadIdx.x;  // 64
    float c = cnt[g];
    c = c < 1.f ? 1.f : c;
    float p = pool[g * 64 + d] / c;
#pragma unroll
    for (int o = 0; o < 16; ++o) {
        float v = p * fcW[d * 16 + o];
#pragma unroll
        for (int off = 32; off > 0; off >>= 1) v += __shfl_down(v, off);
        if (d == 0) out[g * 16 + o] = v + fcb[o];
    }
}

extern "C" void kernel_launch(void* const* d_in, const int* in_sizes, int n_in,
                              void* d_out, int out_size, void* d_ws, size_t ws_size,
                              hipStream_t stream) {
    const float* x   = (const float*)d_in[0];
    const int*   ei  = (const int*)d_in[1];
    const int*   bat = (const int*)d_in[2];
    const float* W1  = (const float*)d_in[3];
    const float* a1s = (const float*)d_in[4];
    const float* a1d = (const float*)d_in[5];
    const float* b1  = (const float*)d_in[6];
    const float* W2  = (const float*)d_in[7];
    const float* a2s = (const float*)d_in[8];
    const float* a2d = (const float*)d_in[9];
    const float* b2  = (const float*)d_in[10];
    const float* fcb = (const float*)d_in[12];
    const float* fcW = (const float*)d_in[11];
    float* out = (float*)d_out;

    float* ws = (float*)d_ws;
    int* flag = (int*)d_ws;
    float* h    = ws + 256;               // [N,256]
    float* as_  = h + (size_t)NN * 256;   // [N,4]
    float* ad_  = as_ + NN * 4;           // [N,4]
    unsigned* emax = (unsigned*)(ad_ + NN * 4);  // [N,4]
    float* den  = (float*)emax + NN * 4;  // [N,4]
    float* xa   = den + NN * 4;           // [N,64] layer1 accum -> x2
    float* xb   = xa + NN * 64;           // [N,64] layer2 accum -> x3
    float* pool = xb + NN * 64;           // [500,64]
    float* cnt  = pool + NG * 64;         // [500]

    const int eb = (ETOT + 255) / 256;          // edge-per-thread blocks
    const int ab = (ETOT * 64 + 255) / 256;     // wave-per-edge blocks (212500)
    const int nb = (NN * 64 + 255) / 256;       // 12500
    const dim3 g1((NN + 63) / 64, 4);

    k_detect<<<1, 1, 0, stream>>>(ei, flag);

    // ---- layer 1 ----
    k_gemm<128><<<g1, 256, 0, stream>>>(x, W1, h, NN);
    k_alpha<<<NN, 256, 0, stream>>>(h, a1s, a1d, as_, ad_);
    k_init_layer<<<nb, 256, 0, stream>>>(emax, den, xa);
    k_edge_max<<<eb, 256, 0, stream>>>(ei, flag, as_, ad_, emax);
    k_edge_sum<<<eb, 256, 0, stream>>>(ei, flag, as_, ad_, emax, den);
    k_edge_aggr<<<ab, 256, 0, stream>>>(ei, flag, as_, ad_, emax, den, h, xa);
    k_finalize<<<nb, 256, 0, stream>>>(xa, b1);

    // ---- layer 2 ----
    k_gemm<64><<<g1, 256, 0, stream>>>(xa, W2, h, NN);
    k_alpha<<<NN, 256, 0, stream>>>(h, a2s, a2d, as_, ad_);
    k_init_layer<<<nb, 256, 0, stream>>>(emax, den, xb);
    k_edge_max<<<eb, 256, 0, stream>>>(ei, flag, as_, ad_, emax);
    k_edge_sum<<<eb, 256, 0, stream>>>(ei, flag, as_, ad_, emax, den);
    k_edge_aggr<<<ab, 256, 0, stream>>>(ei, flag, as_, ad_, emax, den, h, xb);
    k_finalize<<<nb, 256, 0, stream>>>(xb, b2);

    // ---- pool + fc ----
    k_zero_pool<<<(NG * 64 + 255) / 256, 256, 0, stream>>>(pool, cnt);
    k_pool<<<(NN * 64 + 255) / 256, 256, 0, stream>>>(xb, bat, flag, pool, cnt);
    k_fc<<<NG, 64, 0, stream>>>(pool, cnt, fcW, fcb, out);
}

// Round 2
// 1062.012 us; speedup vs baseline: 1.2864x; 1.2864x over previous
//
#include <hip/hip_runtime.h>
#include <hip/hip_bf16.h>

#define NN 50000
#define EE 800000
#define ETOT 850000
#define NG 500

// Detect whether index arrays are int64 (stride 2 in 32-bit words) or int32.
// Node ids < 50000 << 2^31, so for int64 every odd word is 0.
__global__ void k_detect(const int* __restrict__ ei, int* __restrict__ flag) {
    int s = 2;
    for (int i = 0; i < 64; ++i) {
        if (ei[2 * i + 1] != 0) { s = 1; break; }
    }
    *flag = s;
}

// One-time: int64/int32 edge list -> int32 src/dst arrays with self-loops appended.
__global__ __launch_bounds__(256) void k_prep(const int* __restrict__ ei,
                                              const int* __restrict__ flag,
                                              int* __restrict__ src32,
                                              int* __restrict__ dst32) {
    int e = blockIdx.x * 256 + threadIdx.x;
    if (e >= ETOT) return;
    int st = *flag;
    if (e < EE) {
        src32[e] = ei[(size_t)st * e];
        dst32[e] = ei[(size_t)st * (EE + e)];
    } else {
        src32[e] = dst32[e] = e - EE;  // self-loop
    }
}

// C[M,256] = A[M,K] @ B[K,256], fp32 tiled. BM=64,BN=64(one head),BK=16.
// C stored INTERLEAVED: C[m*256 + dim*4 + head]  (head-innermost float4 per dim).
// Fused epilogue: alpha_s/alpha_d dot products per (node, head).
template <int K>
__global__ __launch_bounds__(256) void k_gemm(const float* __restrict__ A,
                                              const float* __restrict__ B,
                                              const float* __restrict__ asrc,
                                              const float* __restrict__ adst,
                                              float* __restrict__ C,
                                              float* __restrict__ os,
                                              float* __restrict__ od, int M) {
    __shared__ float As[16][68];  // pad 4 -> 16B-aligned b128 frag reads
    __shared__ float Bs[16][68];
    const int m0 = blockIdx.x * 64, n0 = blockIdx.y * 64, head = blockIdx.y;
    const int tid = threadIdx.x;
    const int tx = tid & 15, ty = tid >> 4;
    float acc[4][4] = {};
    for (int k0 = 0; k0 < K; k0 += 16) {
        {
            int c = tid & 15, r0 = tid >> 4;
#pragma unroll
            for (int rr = 0; rr < 4; ++rr) {
                int r = r0 + rr * 16, gm = m0 + r;
                As[c][r] = (gm < M) ? A[gm * K + k0 + c] : 0.f;
            }
        }
        {
            int j = tid & 63, cb = tid >> 6;
#pragma unroll
            for (int cc = 0; cc < 4; ++cc) {
                int k = cb + cc * 4;
                Bs[k][j] = B[(k0 + k) * 256 + n0 + j];
            }
        }
        __syncthreads();
#pragma unroll
        for (int k = 0; k < 16; ++k) {
            float a[4], b[4];
            *(float4*)a = *(const float4*)&As[k][ty * 4];
            *(float4*)b = *(const float4*)&Bs[k][tx * 4];
#pragma unroll
            for (int i = 0; i < 4; ++i)
#pragma unroll
                for (int j = 0; j < 4; ++j) acc[i][j] += a[i] * b[j];
        }
        __syncthreads();
    }
    // interleaved store: [m][dim][head]
#pragma unroll
    for (int i = 0; i < 4; ++i) {
        int gm = m0 + ty * 4 + i;
        if (gm < M) {
#pragma unroll
            for (int j = 0; j < 4; ++j)
                C[gm * 256 + (tx * 4 + j) * 4 + head] = acc[i][j];
        }
    }
    // fused alpha_s / alpha_d
    float4 av = *(const float4*)&asrc[head * 64 + tx * 4];
    float4 dv = *(const float4*)&adst[head * 64 + tx * 4];
    float ps[4], pd[4];
#pragma unroll
    for (int i = 0; i < 4; ++i) {
        ps[i] = acc[i][0] * av.x + acc[i][1] * av.y + acc[i][2] * av.z + acc[i][3] * av.w;
        pd[i] = acc[i][0] * dv.x + acc[i][1] * dv.y + acc[i][2] * dv.z + acc[i][3] * dv.w;
    }
#pragma unroll
    for (int off = 1; off < 16; off <<= 1) {
#pragma unroll
        for (int i = 0; i < 4; ++i) {
            ps[i] += __shfl_xor(ps[i], off);
            pd[i] += __shfl_xor(pd[i], off);
        }
    }
    if (tx == 0) {
#pragma unroll
        for (int i = 0; i < 4; ++i) {
            int gm = m0 + ty * 4 + i;
            if (gm < M) {
                os[gm * 4 + head] = ps[i];
                od[gm * 4 + head] = pd[i];
            }
        }
    }
}

__global__ __launch_bounds__(256) void k_init_layer(float* __restrict__ den,
                                                    float* __restrict__ xacc) {
    int i = blockIdx.x * blockDim.x + threadIdx.x;
    if (i < NN * 4) den[i] = 0.f;
    if (i < NN * 64) xacc[i] = 0.f;
}

// Thread per edge: u = exp(leaky(as[src]+ad[dst])) (no max shift -- logits are
// O(±8), exp cannot overflow fp32; normalization is mathematically identical).
__global__ __launch_bounds__(256) void k_edge_alpha(const int* __restrict__ src32,
                                                    const int* __restrict__ dst32,
                                                    const float* __restrict__ as_,
                                                    const float* __restrict__ ad_,
                                                    float* __restrict__ u,
                                                    float* __restrict__ den) {
    int e = blockIdx.x * 256 + threadIdx.x;
    if (e >= ETOT) return;
    int s = src32[e], d = dst32[e];
    float4 sv = *(const float4*)(as_ + s * 4);
    float4 dv = *(const float4*)(ad_ + d * 4);
    float v[4] = {sv.x + dv.x, sv.y + dv.y, sv.z + dv.z, sv.w + dv.w};
    float uu[4];
#pragma unroll
    for (int hh = 0; hh < 4; ++hh) {
        float x = v[hh];
        x = x > 0.f ? x : 0.2f * x;
        uu[hh] = __expf(x);
        atomicAdd(den + d * 4 + hh, uu[hh]);
    }
    *(float4*)(u + e * 4) = make_float4(uu[0], uu[1], uu[2], uu[3]);
}

// den -> 0.25/den in place (head-mean folded in).
__global__ __launch_bounds__(256) void k_recip(float* __restrict__ den) {
    int i = blockIdx.x * blockDim.x + threadIdx.x;
    if (i < NN * 4) den[i] = 0.25f / den[i];
}

// Wave per edge, lane = dim. h interleaved [n][dim][head] -> ONE b128 gather.
__global__ __launch_bounds__(256) void k_edge_aggr(const int* __restrict__ src32,
                                                   const int* __restrict__ dst32,
                                                   const float* __restrict__ u,
                                                   const float* __restrict__ dinv,
                                                   const float* __restrict__ h,
                                                   float* __restrict__ xacc) {
    int wave = (blockIdx.x * 256 + threadIdx.x) >> 6;
    int lane = threadIdx.x & 63;
    if (wave >= ETOT) return;
    int s = src32[wave], d = dst32[wave];
    float4 u4 = *(const float4*)(u + wave * 4);
    float4 v4 = *(const float4*)(dinv + d * 4);
    float4 hv = *(const float4*)(h + s * 256 + lane * 4);
    float sum = (u4.x * v4.x) * hv.x + (u4.y * v4.y) * hv.y +
                (u4.z * v4.z) * hv.z + (u4.w * v4.w) * hv.w;
    atomicAdd(xacc + d * 64 + lane, sum);
}

__global__ __launch_bounds__(256) void k_finalize(float* __restrict__ xacc,
                                                  const float* __restrict__ b) {
    int i = blockIdx.x * blockDim.x + threadIdx.x;
    if (i < NN * 64) {
        float v = xacc[i] + b[i & 63];
        xacc[i] = v > 0.f ? v : 0.f;
    }
}

// batch is SORTED: binary-search the node range per graph -> no atomics.
__global__ __launch_bounds__(64) void k_pool_fc(const float* __restrict__ x3,
                                                const int* __restrict__ batch,
                                                const int* __restrict__ flag,
                                                const float* __restrict__ fcW,
                                                const float* __restrict__ fcb,
                                                float* __restrict__ out) {
    int g = blockIdx.x;
    int d = threadIdx.x;  // 64
    int st = *flag;
    int lo = 0, hi = NN;
    while (lo < hi) { int mid = (lo + hi) >> 1; if (batch[(size_t)st * mid] < g) lo = mid + 1; else hi = mid; }
    int start = lo;
    hi = NN;
    while (lo < hi) { int mid = (lo + hi) >> 1; if (batch[(size_t)st * mid] < g + 1) lo = mid + 1; else hi = mid; }
    int end = lo;
    float sum = 0.f;
    for (int n = start; n < end; ++n) sum += x3[n * 64 + d];
    float c = (float)(end - start);
    if (c < 1.f) c = 1.f;
    float p = sum / c;
#pragma unroll
    for (int o = 0; o < 16; ++o) {
        float v = p * fcW[d * 16 + o];
#pragma unroll
        for (int off = 32; off > 0; off >>= 1) v += __shfl_down(v, off);
        if (d == 0) out[g * 16 + o] = v + fcb[o];
    }
}

extern "C" void kernel_launch(void* const* d_in, const int* in_sizes, int n_in,
                              void* d_out, int out_size, void* d_ws, size_t ws_size,
                              hipStream_t stream) {
    const float* x   = (const float*)d_in[0];
    const int*   ei  = (const int*)d_in[1];
    const int*   bat = (const int*)d_in[2];
    const float* W1  = (const float*)d_in[3];
    const float* a1s = (const float*)d_in[4];
    const float* a1d = (const float*)d_in[5];
    const float* b1  = (const float*)d_in[6];
    const float* W2  = (const float*)d_in[7];
    const float* a2s = (const float*)d_in[8];
    const float* a2d = (const float*)d_in[9];
    const float* b2  = (const float*)d_in[10];
    const float* fcW = (const float*)d_in[11];
    const float* fcb = (const float*)d_in[12];
    float* out = (float*)d_out;

    float* ws = (float*)d_ws;
    int* flag = (int*)d_ws;
    float* h    = ws + 256;                      // [N,256] interleaved [n][dim][head]
    float* as_  = h + (size_t)NN * 256;          // [N,4]
    float* ad_  = as_ + NN * 4;                  // [N,4]
    float* den  = ad_ + NN * 4;                  // [N,4] -> dinv in place
    float* u    = den + NN * 4;                  // [E,4]
    int*  src32 = (int*)(u + (size_t)ETOT * 4);  // [E]
    int*  dst32 = src32 + ETOT;                  // [E]
    float* xacc = (float*)(dst32 + ETOT);        // [N,64] (layer1 out, reused layer2)

    const int eb = (ETOT + 255) / 256;        // 3321
    const int ab = (ETOT * 64 + 255) / 256;   // 212500
    const int nb = (NN * 64 + 255) / 256;     // 12500
    const dim3 g1((NN + 63) / 64, 4);

    k_detect<<<1, 1, 0, stream>>>(ei, flag);
    k_prep<<<eb, 256, 0, stream>>>(ei, flag, src32, dst32);

    // ---- layer 1 ----
    k_gemm<128><<<g1, 256, 0, stream>>>(x, W1, a1s, a1d, h, as_, ad_, NN);
    k_init_layer<<<nb, 256, 0, stream>>>(den, xacc);
    k_edge_alpha<<<eb, 256, 0, stream>>>(src32, dst32, as_, ad_, u, den);
    k_recip<<<(NN * 4 + 255) / 256, 256, 0, stream>>>(den);
    k_edge_aggr<<<ab, 256, 0, stream>>>(src32, dst32, u, den, h, xacc);
    k_finalize<<<nb, 256, 0, stream>>>(xacc, b1);

    // ---- layer 2 (xacc is both GEMM input and, after init, the new accum) ----
    k_gemm<64><<<g1, 256, 0, stream>>>(xacc, W2, a2s, a2d, h, as_, ad_, NN);
    k_init_layer<<<nb, 256, 0, stream>>>(den, xacc);
    k_edge_alpha<<<eb, 256, 0, stream>>>(src32, dst32, as_, ad_, u, den);
    k_recip<<<(NN * 4 + 255) / 256, 256, 0, stream>>>(den);
    k_edge_aggr<<<ab, 256, 0, stream>>>(src32, dst32, u, den, h, xacc);
    k_finalize<<<nb, 256, 0, stream>>>(xacc, b2);

    // ---- pool + fc ----
    k_pool_fc<<<NG, 64, 0, stream>>>(xacc, bat, flag, fcW, fcb, out);
}

// Round 3
// 782.176 us; speedup vs baseline: 1.7466x; 1.3578x over previous
//
#include <hip/hip_runtime.h>
#include <hip/hip_bf16.h>

#define NN 50000
#define EE 800000
#define ETOT 850000
#define NG 500

// int64 vs int32 index detect: node ids < 50000, so int64 => odd words all 0.
__global__ void k_detect(const int* __restrict__ ei, int* __restrict__ flag) {
    unsigned long long b = __ballot(ei[2 * threadIdx.x + 1] != 0);
    if (threadIdx.x == 0) *flag = b ? 1 : 2;
}

// edge list (either width) -> int32 src/dst with self-loops appended.
__global__ __launch_bounds__(256) void k_prep(const int* __restrict__ ei,
                                              const int* __restrict__ flag,
                                              int* __restrict__ src32,
                                              int* __restrict__ dst32) {
    int e = blockIdx.x * 256 + threadIdx.x;
    if (e >= ETOT) return;
    int st = *flag;
    if (e < EE) {
        src32[e] = ei[(size_t)st * e];
        dst32[e] = ei[(size_t)st * (EE + e)];
    } else {
        src32[e] = dst32[e] = e - EE;  // self-loop
    }
}

__global__ __launch_bounds__(256) void k_zero_deg(int* __restrict__ deg) {
    int i = blockIdx.x * 256 + threadIdx.x;
    if (i < NN) deg[i] = 0;
}

__global__ __launch_bounds__(256) void k_hist(const int* __restrict__ dst32,
                                              int* __restrict__ deg) {
    int e = blockIdx.x * 256 + threadIdx.x;
    if (e < ETOT) atomicAdd(&deg[dst32[e]], 1);
}

// Single-block exclusive scan of deg[NN] -> rowptr/cursor.
__global__ __launch_bounds__(1024) void k_scan(const int* __restrict__ deg,
                                               int* __restrict__ rowptr,
                                               int* __restrict__ cursor) {
    __shared__ int lsum[1024];
    int tid = threadIdx.x;
    const int per = (NN + 1023) / 1024;  // 49
    int base = tid * per;
    int s = 0;
    for (int i = 0; i < per; ++i) {
        int idx = base + i;
        if (idx < NN) s += deg[idx];
    }
    lsum[tid] = s;
    __syncthreads();
    for (int d = 1; d < 1024; d <<= 1) {
        int v = (tid >= d) ? lsum[tid - d] : 0;
        __syncthreads();
        lsum[tid] += v;
        __syncthreads();
    }
    int off = lsum[tid] - s;  // exclusive prefix
    for (int i = 0; i < per; ++i) {
        int idx = base + i;
        if (idx < NN) {
            rowptr[idx] = off;
            cursor[idx] = off;
            off += deg[idx];
        }
    }
    if (tid == 1023) rowptr[NN] = off;
}

__global__ __launch_bounds__(256) void k_scatter(const int* __restrict__ src32,
                                                 const int* __restrict__ dst32,
                                                 int* __restrict__ cursor,
                                                 int* __restrict__ csr_src) {
    int e = blockIdx.x * 256 + threadIdx.x;
    if (e >= ETOT) return;
    int pos = atomicAdd(&cursor[dst32[e]], 1);
    csr_src[pos] = src32[e];
}

// C[M,256] = A[M,K] @ B[K,256], fp32 tiled. BM=64,BN=64(one head),BK=16.
// C stored INTERLEAVED: C[m*256 + dim*4 + head]. Fused alpha_s/alpha_d epilogue.
template <int K>
__global__ __launch_bounds__(256) void k_gemm(const float* __restrict__ A,
                                              const float* __restrict__ B,
                                              const float* __restrict__ asrc,
                                              const float* __restrict__ adst,
                                              float* __restrict__ C,
                                              float* __restrict__ os,
                                              float* __restrict__ od, int M) {
    __shared__ float As[16][68];
    __shared__ float Bs[16][68];
    const int m0 = blockIdx.x * 64, n0 = blockIdx.y * 64, head = blockIdx.y;
    const int tid = threadIdx.x;
    const int tx = tid & 15, ty = tid >> 4;
    float acc[4][4] = {};
    for (int k0 = 0; k0 < K; k0 += 16) {
        {
            int c = tid & 15, r0 = tid >> 4;
#pragma unroll
            for (int rr = 0; rr < 4; ++rr) {
                int r = r0 + rr * 16, gm = m0 + r;
                As[c][r] = (gm < M) ? A[gm * K + k0 + c] : 0.f;
            }
        }
        {
            int j = tid & 63, cb = tid >> 6;
#pragma unroll
            for (int cc = 0; cc < 4; ++cc) {
                int k = cb + cc * 4;
                Bs[k][j] = B[(k0 + k) * 256 + n0 + j];
            }
        }
        __syncthreads();
#pragma unroll
        for (int k = 0; k < 16; ++k) {
            float a[4], b[4];
            *(float4*)a = *(const float4*)&As[k][ty * 4];
            *(float4*)b = *(const float4*)&Bs[k][tx * 4];
#pragma unroll
            for (int i = 0; i < 4; ++i)
#pragma unroll
                for (int j = 0; j < 4; ++j) acc[i][j] += a[i] * b[j];
        }
        __syncthreads();
    }
#pragma unroll
    for (int i = 0; i < 4; ++i) {
        int gm = m0 + ty * 4 + i;
        if (gm < M) {
#pragma unroll
            for (int j = 0; j < 4; ++j)
                C[gm * 256 + (tx * 4 + j) * 4 + head] = acc[i][j];
        }
    }
    float4 av = *(const float4*)&asrc[head * 64 + tx * 4];
    float4 dv = *(const float4*)&adst[head * 64 + tx * 4];
    float ps[4], pd[4];
#pragma unroll
    for (int i = 0; i < 4; ++i) {
        ps[i] = acc[i][0] * av.x + acc[i][1] * av.y + acc[i][2] * av.z + acc[i][3] * av.w;
        pd[i] = acc[i][0] * dv.x + acc[i][1] * dv.y + acc[i][2] * dv.z + acc[i][3] * dv.w;
    }
#pragma unroll
    for (int off = 1; off < 16; off <<= 1) {
#pragma unroll
        for (int i = 0; i < 4; ++i) {
            ps[i] += __shfl_xor(ps[i], off);
            pd[i] += __shfl_xor(pd[i], off);
        }
    }
    if (tx == 0) {
#pragma unroll
        for (int i = 0; i < 4; ++i) {
            int gm = m0 + ty * 4 + i;
            if (gm < M) {
                os[gm * 4 + head] = ps[i];
                od[gm * 4 + head] = pd[i];
            }
        }
    }
}

__device__ __forceinline__ float lrelu_exp(float x) {
    x = x > 0.f ? x : 0.2f * x;
    return __expf(x);
}

// Wave per dst node. Pass 1: den (lanes parallel over edges). Pass 2: alpha
// shuffle-broadcast, lanes = dims, register accumulate. Fused bias+relu store.
// No atomics, no init, single 256B store per node.
__global__ __launch_bounds__(256) void k_aggr(const int* __restrict__ rowptr,
                                              const int* __restrict__ csr_src,
                                              const float* __restrict__ as_,
                                              const float* __restrict__ ad_,
                                              const float* __restrict__ h,
                                              const float* __restrict__ bias,
                                              float* __restrict__ out) {
    int d = (blockIdx.x * 256 + threadIdx.x) >> 6;
    int lane = threadIdx.x & 63;
    if (d >= NN) return;
    int beg = rowptr[d], end = rowptr[d + 1];
    float4 adv = *(const float4*)(ad_ + d * 4);
    // pass 1: denominator
    float4 den = make_float4(0.f, 0.f, 0.f, 0.f);
    for (int i = beg + lane; i < end; i += 64) {
        int s = csr_src[i];
        float4 sv = *(const float4*)(as_ + s * 4);
        den.x += lrelu_exp(sv.x + adv.x);
        den.y += lrelu_exp(sv.y + adv.y);
        den.z += lrelu_exp(sv.z + adv.z);
        den.w += lrelu_exp(sv.w + adv.w);
    }
#pragma unroll
    for (int off = 32; off > 0; off >>= 1) {
        den.x += __shfl_xor(den.x, off);
        den.y += __shfl_xor(den.y, off);
        den.z += __shfl_xor(den.z, off);
        den.w += __shfl_xor(den.w, off);
    }
    float4 dinv = make_float4(0.25f / den.x, 0.25f / den.y,
                              0.25f / den.z, 0.25f / den.w);
    // pass 2: weighted aggregation, chunks of 64 edges
    float acc = 0.f;
    for (int chunk = beg; chunk < end; chunk += 64) {
        int i = chunk + lane;
        int s = 0;
        float4 al = make_float4(0.f, 0.f, 0.f, 0.f);
        if (i < end) {
            s = csr_src[i];
            float4 sv = *(const float4*)(as_ + s * 4);
            al.x = lrelu_exp(sv.x + adv.x) * dinv.x;
            al.y = lrelu_exp(sv.y + adv.y) * dinv.y;
            al.z = lrelu_exp(sv.z + adv.z) * dinv.z;
            al.w = lrelu_exp(sv.w + adv.w) * dinv.w;
        }
        int cnt = end - chunk;
        if (cnt > 64) cnt = 64;
        for (int j = 0; j < cnt; ++j) {
            int sj = __shfl(s, j);
            float a0 = __shfl(al.x, j), a1 = __shfl(al.y, j);
            float a2 = __shfl(al.z, j), a3 = __shfl(al.w, j);
            float4 hv = *(const float4*)(h + sj * 256 + lane * 4);
            acc += a0 * hv.x + a1 * hv.y + a2 * hv.z + a3 * hv.w;
        }
    }
    float v = acc + bias[lane];
    out[d * 64 + lane] = v > 0.f ? v : 0.f;
}

// batch is SORTED: binary-search the node range per graph -> no atomics.
__global__ __launch_bounds__(64) void k_pool_fc(const float* __restrict__ x3,
                                                const int* __restrict__ batch,
                                                const int* __restrict__ flag,
                                                const float* __restrict__ fcW,
                                                const float* __restrict__ fcb,
                                                float* __restrict__ out) {
    int g = blockIdx.x;
    int d = threadIdx.x;  // 64
    int st = *flag;
    int lo = 0, hi = NN;
    while (lo < hi) { int mid = (lo + hi) >> 1; if (batch[(size_t)st * mid] < g) lo = mid + 1; else hi = mid; }
    int start = lo;
    hi = NN;
    while (lo < hi) { int mid = (lo + hi) >> 1; if (batch[(size_t)st * mid] < g + 1) lo = mid + 1; else hi = mid; }
    int end = lo;
    float sum = 0.f;
    for (int n = start; n < end; ++n) sum += x3[n * 64 + d];
    float c = (float)(end - start);
    if (c < 1.f) c = 1.f;
    float p = sum / c;
#pragma unroll
    for (int o = 0; o < 16; ++o) {
        float v = p * fcW[d * 16 + o];
#pragma unroll
        for (int off = 32; off > 0; off >>= 1) v += __shfl_down(v, off);
        if (d == 0) out[g * 16 + o] = v + fcb[o];
    }
}

extern "C" void kernel_launch(void* const* d_in, const int* in_sizes, int n_in,
                              void* d_out, int out_size, void* d_ws, size_t ws_size,
                              hipStream_t stream) {
    const float* x   = (const float*)d_in[0];
    const int*   ei  = (const int*)d_in[1];
    const int*   bat = (const int*)d_in[2];
    const float* W1  = (const float*)d_in[3];
    const float* a1s = (const float*)d_in[4];
    const float* a1d = (const float*)d_in[5];
    const float* b1  = (const float*)d_in[6];
    const float* W2  = (const float*)d_in[7];
    const float* a2s = (const float*)d_in[8];
    const float* a2d = (const float*)d_in[9];
    const float* b2  = (const float*)d_in[10];
    const float* fcW = (const float*)d_in[11];
    const float* fcb = (const float*)d_in[12];
    float* out = (float*)d_out;

    float* ws = (float*)d_ws;
    int* flag = (int*)d_ws;                       // [1] (+pad to 256)
    float* h     = ws + 256;                      // [N,256] interleaved [n][dim][head]
    float* as_   = h + (size_t)NN * 256;          // [N,4]
    float* ad_   = as_ + NN * 4;                  // [N,4]
    float* xacc  = ad_ + NN * 4;                  // [N,64]
    int* src32   = (int*)(xacc + (size_t)NN * 64);// [E]
    int* dst32   = src32 + ETOT;                  // [E]
    int* deg     = dst32 + ETOT;                  // [N]
    int* rowptr  = deg + NN;                      // [N+1]
    int* cursor  = rowptr + NN + 1;               // [N]
    int* csr_src = cursor + NN;                   // [E]

    const int eb = (ETOT + 255) / 256;   // 3321
    const int wb = (NN * 64 + 255) / 256; // 12500 (wave-per-node blocks)

    // ---- one-time per call: indices + dst-CSR ----
    k_detect<<<1, 64, 0, stream>>>(ei, flag);
    k_prep<<<eb, 256, 0, stream>>>(ei, flag, src32, dst32);
    k_zero_deg<<<(NN + 255) / 256, 256, 0, stream>>>(deg);
    k_hist<<<eb, 256, 0, stream>>>(dst32, deg);
    k_scan<<<1, 1024, 0, stream>>>(deg, rowptr, cursor);
    k_scatter<<<eb, 256, 0, stream>>>(src32, dst32, cursor, csr_src);

    const dim3 g1((NN + 63) / 64, 4);
    // ---- layer 1 ----
    k_gemm<128><<<g1, 256, 0, stream>>>(x, W1, a1s, a1d, h, as_, ad_, NN);
    k_aggr<<<wb, 256, 0, stream>>>(rowptr, csr_src, as_, ad_, h, b1, xacc);
    // ---- layer 2 ----
    k_gemm<64><<<g1, 256, 0, stream>>>(xacc, W2, a2s, a2d, h, as_, ad_, NN);
    k_aggr<<<wb, 256, 0, stream>>>(rowptr, csr_src, as_, ad_, h, b2, xacc);
    // ---- pool + fc ----
    k_pool_fc<<<NG, 64, 0, stream>>>(xacc, bat, flag, fcW, fcb, out);
}

// Round 4
// 663.686 us; speedup vs baseline: 2.0585x; 1.1785x over previous
//
#include <hip/hip_runtime.h>
#include <hip/hip_bf16.h>

#define NN 50000
#define EE 800000
#define ETOT 850000
#define NG 500
#define NBLK ((NN + 255) / 256)  // 196 scan blocks

// int64 vs int32 index detect: node ids < 50000, so int64 => odd words all 0.
__global__ void k_detect(const int* __restrict__ ei, int* __restrict__ flag) {
    unsigned long long b = __ballot(ei[2 * threadIdx.x + 1] != 0);
    if (threadIdx.x == 0) *flag = b ? 1 : 2;
}

// edge list (either width) -> int32 src/dst with self-loops appended.
__global__ __launch_bounds__(256) void k_prep(const int* __restrict__ ei,
                                              const int* __restrict__ flag,
                                              int* __restrict__ src32,
                                              int* __restrict__ dst32) {
    int e = blockIdx.x * 256 + threadIdx.x;
    if (e >= ETOT) return;
    int st = *flag;
    if (e < EE) {
        src32[e] = ei[(size_t)st * e];
        dst32[e] = ei[(size_t)st * (EE + e)];
    } else {
        src32[e] = dst32[e] = e - EE;  // self-loop
    }
}

__global__ __launch_bounds__(256) void k_zero_deg(int* __restrict__ deg) {
    int i = blockIdx.x * 256 + threadIdx.x;
    if (i < NN) deg[i] = 0;
}

__global__ __launch_bounds__(256) void k_hist(const int* __restrict__ dst32,
                                              int* __restrict__ deg) {
    int e = blockIdx.x * 256 + threadIdx.x;
    if (e < ETOT) atomicAdd(&deg[dst32[e]], 1);
}

// ---- 3-phase multi-block exclusive scan of deg[NN] ----
__global__ __launch_bounds__(256) void k_blocksum(const int* __restrict__ deg,
                                                  int* __restrict__ bsum) {
    __shared__ int l[256];
    int gid = blockIdx.x * 256 + threadIdx.x;
    int tid = threadIdx.x;
    l[tid] = (gid < NN) ? deg[gid] : 0;
    __syncthreads();
    for (int o = 128; o > 0; o >>= 1) {
        if (tid < o) l[tid] += l[tid + o];
        __syncthreads();
    }
    if (tid == 0) bsum[blockIdx.x] = l[0];
}

__global__ __launch_bounds__(256) void k_scan_bsum(const int* __restrict__ bsum,
                                                   int* __restrict__ boff) {
    __shared__ int l[256];
    int tid = threadIdx.x;
    int v = (tid < NBLK) ? bsum[tid] : 0;
    l[tid] = v;
    __syncthreads();
    for (int d = 1; d < 256; d <<= 1) {
        int t = (tid >= d) ? l[tid - d] : 0;
        __syncthreads();
        l[tid] += t;
        __syncthreads();
    }
    if (tid < NBLK) boff[tid] = l[tid] - v;  // exclusive
}

__global__ __launch_bounds__(256) void k_scan_final(const int* __restrict__ deg,
                                                    const int* __restrict__ boff,
                                                    int* __restrict__ rowptr,
                                                    int* __restrict__ cursor) {
    __shared__ int l[256];
    int gid = blockIdx.x * 256 + threadIdx.x;
    int tid = threadIdx.x;
    int v = (gid < NN) ? deg[gid] : 0;
    l[tid] = v;
    __syncthreads();
    for (int d = 1; d < 256; d <<= 1) {
        int t = (tid >= d) ? l[tid - d] : 0;
        __syncthreads();
        l[tid] += t;
        __syncthreads();
    }
    int ex = l[tid] - v + boff[blockIdx.x];
    if (gid < NN) { rowptr[gid] = ex; cursor[gid] = ex; }
    if (gid == 0) rowptr[NN] = ETOT;  // total incl. self-loops is a constant
}

__global__ __launch_bounds__(256) void k_scatter(const int* __restrict__ src32,
                                                 const int* __restrict__ dst32,
                                                 int* __restrict__ cursor,
                                                 int* __restrict__ csr_src) {
    int e = blockIdx.x * 256 + threadIdx.x;
    if (e >= ETOT) return;
    int pos = atomicAdd(&cursor[dst32[e]], 1);
    csr_src[pos] = src32[e];
}

// C[M,256] = A[M,K] @ B[K,256], fp32 tiled. BM=64,BN=64(one head),BK=16.
// C stored INTERLEAVED: C[m*256 + dim*4 + head]. Fused alpha_s/alpha_d epilogue.
template <int K>
__global__ __launch_bounds__(256) void k_gemm(const float* __restrict__ A,
                                              const float* __restrict__ B,
                                              const float* __restrict__ asrc,
                                              const float* __restrict__ adst,
                                              float* __restrict__ C,
                                              float* __restrict__ os,
                                              float* __restrict__ od, int M) {
    __shared__ float As[16][68];
    __shared__ float Bs[16][68];
    const int m0 = blockIdx.x * 64, n0 = blockIdx.y * 64, head = blockIdx.y;
    const int tid = threadIdx.x;
    const int tx = tid & 15, ty = tid >> 4;
    float acc[4][4] = {};
    for (int k0 = 0; k0 < K; k0 += 16) {
        {
            int c = tid & 15, r0 = tid >> 4;
#pragma unroll
            for (int rr = 0; rr < 4; ++rr) {
                int r = r0 + rr * 16, gm = m0 + r;
                As[c][r] = (gm < M) ? A[gm * K + k0 + c] : 0.f;
            }
        }
        {
            int j = tid & 63, cb = tid >> 6;
#pragma unroll
            for (int cc = 0; cc < 4; ++cc) {
                int k = cb + cc * 4;
                Bs[k][j] = B[(k0 + k) * 256 + n0 + j];
            }
        }
        __syncthreads();
#pragma unroll
        for (int k = 0; k < 16; ++k) {
            float a[4], b[4];
            *(float4*)a = *(const float4*)&As[k][ty * 4];
            *(float4*)b = *(const float4*)&Bs[k][tx * 4];
#pragma unroll
            for (int i = 0; i < 4; ++i)
#pragma unroll
                for (int j = 0; j < 4; ++j) acc[i][j] += a[i] * b[j];
        }
        __syncthreads();
    }
#pragma unroll
    for (int i = 0; i < 4; ++i) {
        int gm = m0 + ty * 4 + i;
        if (gm < M) {
#pragma unroll
            for (int j = 0; j < 4; ++j)
                C[gm * 256 + (tx * 4 + j) * 4 + head] = acc[i][j];
        }
    }
    float4 av = *(const float4*)&asrc[head * 64 + tx * 4];
    float4 dv = *(const float4*)&adst[head * 64 + tx * 4];
    float ps[4], pd[4];
#pragma unroll
    for (int i = 0; i < 4; ++i) {
        ps[i] = acc[i][0] * av.x + acc[i][1] * av.y + acc[i][2] * av.z + acc[i][3] * av.w;
        pd[i] = acc[i][0] * dv.x + acc[i][1] * dv.y + acc[i][2] * dv.z + acc[i][3] * dv.w;
    }
#pragma unroll
    for (int off = 1; off < 16; off <<= 1) {
#pragma unroll
        for (int i = 0; i < 4; ++i) {
            ps[i] += __shfl_xor(ps[i], off);
            pd[i] += __shfl_xor(pd[i], off);
        }
    }
    if (tx == 0) {
#pragma unroll
        for (int i = 0; i < 4; ++i) {
            int gm = m0 + ty * 4 + i;
            if (gm < M) {
                os[gm * 4 + head] = ps[i];
                od[gm * 4 + head] = pd[i];
            }
        }
    }
}

__device__ __forceinline__ float lrelu_exp(float x) {
    x = x > 0.f ? x : 0.2f * x;
    return __expf(x);
}

// Wave per dst node; avg degree = 17 so chunk 0 is almost always the only one.
// Pass 1 computes den AND caches chunk-0 (s, exp) in registers; pass 2 reuses
// them (no as_ re-gather, no exp recompute on the common path).
__global__ __launch_bounds__(256) void k_aggr(const int* __restrict__ rowptr,
                                              const int* __restrict__ csr_src,
                                              const float* __restrict__ as_,
                                              const float* __restrict__ ad_,
                                              const float* __restrict__ h,
                                              const float* __restrict__ bias,
                                              float* __restrict__ out) {
    int d = (blockIdx.x * 256 + threadIdx.x) >> 6;
    int lane = threadIdx.x & 63;
    if (d >= NN) return;
    int beg = rowptr[d], end = rowptr[d + 1];
    float4 adv = *(const float4*)(ad_ + d * 4);

    // pass 1: denominator + chunk-0 register cache
    int s0 = 0;
    float4 u0 = make_float4(0.f, 0.f, 0.f, 0.f);
    float4 den = make_float4(0.f, 0.f, 0.f, 0.f);
    int i0 = beg + lane;
    if (i0 < end) {
        s0 = csr_src[i0];
        float4 sv = *(const float4*)(as_ + s0 * 4);
        u0.x = lrelu_exp(sv.x + adv.x);
        u0.y = lrelu_exp(sv.y + adv.y);
        u0.z = lrelu_exp(sv.z + adv.z);
        u0.w = lrelu_exp(sv.w + adv.w);
        den = u0;
    }
    for (int i = i0 + 64; i < end; i += 64) {
        int s = csr_src[i];
        float4 sv = *(const float4*)(as_ + s * 4);
        den.x += lrelu_exp(sv.x + adv.x);
        den.y += lrelu_exp(sv.y + adv.y);
        den.z += lrelu_exp(sv.z + adv.z);
        den.w += lrelu_exp(sv.w + adv.w);
    }
#pragma unroll
    for (int off = 32; off > 0; off >>= 1) {
        den.x += __shfl_xor(den.x, off);
        den.y += __shfl_xor(den.y, off);
        den.z += __shfl_xor(den.z, off);
        den.w += __shfl_xor(den.w, off);
    }
    float4 dinv = make_float4(0.25f / den.x, 0.25f / den.y,
                              0.25f / den.z, 0.25f / den.w);

    // pass 2, chunk 0 from registers
    float acc = 0.f;
    {
        float4 al = make_float4(u0.x * dinv.x, u0.y * dinv.y,
                                u0.z * dinv.z, u0.w * dinv.w);
        int cnt = end - beg;
        if (cnt > 64) cnt = 64;
        for (int j = 0; j < cnt; ++j) {
            int sj = __shfl(s0, j);
            float a0 = __shfl(al.x, j), a1 = __shfl(al.y, j);
            float a2 = __shfl(al.z, j), a3 = __shfl(al.w, j);
            float4 hv = *(const float4*)(h + sj * 256 + lane * 4);
            acc += a0 * hv.x + a1 * hv.y + a2 * hv.z + a3 * hv.w;
        }
    }
    // rare chunks >= 1: recompute
    for (int chunk = beg + 64; chunk < end; chunk += 64) {
        int i = chunk + lane;
        int s = 0;
        float4 al = make_float4(0.f, 0.f, 0.f, 0.f);
        if (i < end) {
            s = csr_src[i];
            float4 sv = *(const float4*)(as_ + s * 4);
            al.x = lrelu_exp(sv.x + adv.x) * dinv.x;
            al.y = lrelu_exp(sv.y + adv.y) * dinv.y;
            al.z = lrelu_exp(sv.z + adv.z) * dinv.z;
            al.w = lrelu_exp(sv.w + adv.w) * dinv.w;
        }
        int cnt = end - chunk;
        if (cnt > 64) cnt = 64;
        for (int j = 0; j < cnt; ++j) {
            int sj = __shfl(s, j);
            float a0 = __shfl(al.x, j), a1 = __shfl(al.y, j);
            float a2 = __shfl(al.z, j), a3 = __shfl(al.w, j);
            float4 hv = *(const float4*)(h + sj * 256 + lane * 4);
            acc += a0 * hv.x + a1 * hv.y + a2 * hv.z + a3 * hv.w;
        }
    }
    float v = acc + bias[lane];
    out[d * 64 + lane] = v > 0.f ? v : 0.f;
}

// batch is SORTED: binary-search the node range per graph -> no atomics.
__global__ __launch_bounds__(64) void k_pool_fc(const float* __restrict__ x3,
                                                const int* __restrict__ batch,
                                                const int* __restrict__ flag,
                                                const float* __restrict__ fcW,
                                                const float* __restrict__ fcb,
                                                float* __restrict__ out) {
    int g = blockIdx.x;
    int d = threadIdx.x;  // 64
    int st = *flag;
    int lo = 0, hi = NN;
    while (lo < hi) { int mid = (lo + hi) >> 1; if (batch[(size_t)st * mid] < g) lo = mid + 1; else hi = mid; }
    int start = lo;
    hi = NN;
    while (lo < hi) { int mid = (lo + hi) >> 1; if (batch[(size_t)st * mid] < g + 1) lo = mid + 1; else hi = mid; }
    int end = lo;
    float sum = 0.f;
    for (int n = start; n < end; ++n) sum += x3[n * 64 + d];
    float c = (float)(end - start);
    if (c < 1.f) c = 1.f;
    float p = sum / c;
#pragma unroll
    for (int o = 0; o < 16; ++o) {
        float v = p * fcW[d * 16 + o];
#pragma unroll
        for (int off = 32; off > 0; off >>= 1) v += __shfl_down(v, off);
        if (d == 0) out[g * 16 + o] = v + fcb[o];
    }
}

extern "C" void kernel_launch(void* const* d_in, const int* in_sizes, int n_in,
                              void* d_out, int out_size, void* d_ws, size_t ws_size,
                              hipStream_t stream) {
    const float* x   = (const float*)d_in[0];
    const int*   ei  = (const int*)d_in[1];
    const int*   bat = (const int*)d_in[2];
    const float* W1  = (const float*)d_in[3];
    const float* a1s = (const float*)d_in[4];
    const float* a1d = (const float*)d_in[5];
    const float* b1  = (const float*)d_in[6];
    const float* W2  = (const float*)d_in[7];
    const float* a2s = (const float*)d_in[8];
    const float* a2d = (const float*)d_in[9];
    const float* b2  = (const float*)d_in[10];
    const float* fcW = (const float*)d_in[11];
    const float* fcb = (const float*)d_in[12];
    float* out = (float*)d_out;

    float* ws = (float*)d_ws;
    int* flag = (int*)d_ws;                       // [1] (+pad to 256)
    float* h     = ws + 256;                      // [N,256] interleaved [n][dim][head]
    float* as_   = h + (size_t)NN * 256;          // [N,4]
    float* ad_   = as_ + NN * 4;                  // [N,4]
    float* xacc  = ad_ + NN * 4;                  // [N,64]
    int* src32   = (int*)(xacc + (size_t)NN * 64);// [E]
    int* dst32   = src32 + ETOT;                  // [E]
    int* deg     = dst32 + ETOT;                  // [N]
    int* rowptr  = deg + NN;                      // [N+1]
    int* cursor  = rowptr + NN + 1;               // [N]
    int* csr_src = cursor + NN;                   // [E]
    int* bsum    = csr_src + ETOT;                // [NBLK]
    int* boff    = bsum + NBLK;                   // [NBLK]

    const int eb = (ETOT + 255) / 256;    // 3321
    const int wb = (NN * 64 + 255) / 256; // 12500 (wave-per-node blocks)

    // ---- one-time per call: indices + dst-CSR ----
    k_detect<<<1, 64, 0, stream>>>(ei, flag);
    k_prep<<<eb, 256, 0, stream>>>(ei, flag, src32, dst32);
    k_zero_deg<<<(NN + 255) / 256, 256, 0, stream>>>(deg);
    k_hist<<<eb, 256, 0, stream>>>(dst32, deg);
    k_blocksum<<<NBLK, 256, 0, stream>>>(deg, bsum);
    k_scan_bsum<<<1, 256, 0, stream>>>(bsum, boff);
    k_scan_final<<<NBLK, 256, 0, stream>>>(deg, boff, rowptr, cursor);
    k_scatter<<<eb, 256, 0, stream>>>(src32, dst32, cursor, csr_src);

    const dim3 g1((NN + 63) / 64, 4);
    // ---- layer 1 ----
    k_gemm<128><<<g1, 256, 0, stream>>>(x, W1, a1s, a1d, h, as_, ad_, NN);
    k_aggr<<<wb, 256, 0, stream>>>(rowptr, csr_src, as_, ad_, h, b1, xacc);
    // ---- layer 2 ----
    k_gemm<64><<<g1, 256, 0, stream>>>(xacc, W2, a2s, a2d, h, as_, ad_, NN);
    k_aggr<<<wb, 256, 0, stream>>>(rowptr, csr_src, as_, ad_, h, b2, xacc);
    // ---- pool + fc ----
    k_pool_fc<<<NG, 64, 0, stream>>>(xacc, bat, flag, fcW, fcb, out);
}